// Round 3
// baseline (145.457 us; speedup 1.0000x reference)
//
#include <hip/hip_runtime.h>
#include <hip/hip_bf16.h>

#define HID 1024
#define RANK 16
#define NSEG 64
#define NCHUNK 32          // chunks per segment -> grid = 64*32 = 2048 blocks
#define NXCD 8

__global__ __launch_bounds__(256) void lora_grouped(
    const float* __restrict__ x,      // [N, H]
    const int*   __restrict__ seg,    // [N]
    const float* __restrict__ A,      // [S, H, R]
    const float* __restrict__ B,      // [S, R, H]
    const float* __restrict__ bias,   // [S, H]
    float*       __restrict__ out,    // [N, H]
    int N)
{
    // XCD-bijective swizzle: grid = 2048 = 8*256. blockIdx%8 selects the XCD,
    // so give each XCD a contiguous work range -> 8 segments/XCD -> A+B
    // working set 1 MB, fits the 4 MB per-XCD L2.
    const int work = (blockIdx.x & (NXCD - 1)) * ((NSEG * NCHUNK) / NXCD)
                   + (blockIdx.x >> 3);
    const int s = work >> 5;                 // NCHUNK == 32
    const int c = work & (NCHUNK - 1);
    const int tid  = threadIdx.x;
    const int lane = tid & 63;
    const int wave = tid >> 6;

    __shared__ int   list[256];
    __shared__ int   cnt;
    __shared__ float inter_lds[4][RANK];

    if (tid == 0) cnt = 0;
    __syncthreads();

    // ---- scan this block's 256-token slice for segment matches ----
    const int chunkN = (N + NSEG * NCHUNK - 1) / (NSEG * NCHUNK) * NSEG; // = N/NCHUNK rounded
    const int i0 = c * chunkN;
    const int i1 = min(N, i0 + chunkN);
    for (int i = i0 + tid; i < i1; i += 256) {
        if (seg[i] == s) {
            int p = atomicAdd(&cnt, 1);
            list[p] = i;                     // chunkN <= 256 so no overflow
        }
    }
    __syncthreads();
    const int m = cnt;
    if (m == 0) return;

    const float4* B4 = (const float4*)(B + (size_t)s * RANK * HID);
    const float4* A4 = (const float4*)(A + (size_t)s * HID * RANK);
    const float4  bia = ((const float4*)(bias + (size_t)s * HID))[tid];

    // ---- process tokens in groups of 4 (typically exactly one group) ----
    for (int t = 0; t < m; t += 4) {
        const int nt = min(4, m - t);
        int n[4];
        #pragma unroll
        for (int j = 0; j < 4; ++j)
            n[j] = list[t + (j < nt ? j : nt - 1)];

        // Phase 1: inter[j][r] = sum_h B[s][r][h] * x[n[j]][h]
        // wave owns r = wave*4 .. wave*4+3 ; lane covers h = lane*16..+15
        float4 xv[4][4];
        #pragma unroll
        for (int j = 0; j < 4; ++j) {
            const float4* xr = (const float4*)(x + (size_t)n[j] * HID);
            #pragma unroll
            for (int k = 0; k < 4; ++k) xv[j][k] = xr[lane * 4 + k];
        }

        float acc[4][4];                     // [rr][j]
        #pragma unroll
        for (int rr = 0; rr < 4; ++rr)
            #pragma unroll
            for (int j = 0; j < 4; ++j) acc[rr][j] = 0.f;

        #pragma unroll
        for (int rr = 0; rr < 4; ++rr) {
            const float4* Br = B4 + (size_t)(wave * 4 + rr) * (HID / 4);
            #pragma unroll
            for (int k = 0; k < 4; ++k) {
                float4 b = Br[lane * 4 + k];
                #pragma unroll
                for (int j = 0; j < 4; ++j)
                    acc[rr][j] += b.x * xv[j][k].x + b.y * xv[j][k].y
                                + b.z * xv[j][k].z + b.w * xv[j][k].w;
            }
        }

        #pragma unroll
        for (int rr = 0; rr < 4; ++rr)
            #pragma unroll
            for (int j = 0; j < 4; ++j) {
                float v = acc[rr][j];
                #pragma unroll
                for (int off = 32; off >= 1; off >>= 1)
                    v += __shfl_xor(v, off, 64);
                if (lane == 0) inter_lds[j][wave * 4 + rr] = v;
            }
        __syncthreads();

        // Phase 2: out[n[j]][h] = sum_r A[s][h][r]*inter[j][r] + bias[s][h]
        // thread owns h = tid*4 .. tid*4+3; stream A rows (no hoist, low VGPR)
        float4 av[4][4];
        #pragma unroll
        for (int jh = 0; jh < 4; ++jh)
            #pragma unroll
            for (int q = 0; q < 4; ++q)
                av[jh][q] = A4[(size_t)(tid * 4 + jh) * (RANK / 4) + q];

        #pragma unroll
        for (int j = 0; j < 4; ++j) {
            const float4* I4 = (const float4*)inter_lds[j];
            float4 iv[4];
            #pragma unroll
            for (int q = 0; q < 4; ++q) iv[q] = I4[q];
            float4 o = bia;
            float* op = (float*)&o;
            #pragma unroll
            for (int jh = 0; jh < 4; ++jh) {
                float a = 0.f;
                #pragma unroll
                for (int q = 0; q < 4; ++q)
                    a += av[jh][q].x * iv[q].x + av[jh][q].y * iv[q].y
                       + av[jh][q].z * iv[q].z + av[jh][q].w * iv[q].w;
                op[jh] += a;
            }
            if (j < nt)
                ((float4*)(out + (size_t)n[j] * HID))[tid] = o;
        }
        __syncthreads();
    }
}

extern "C" void kernel_launch(void* const* d_in, const int* in_sizes, int n_in,
                              void* d_out, int out_size, void* d_ws, size_t ws_size,
                              hipStream_t stream) {
    const float* x    = (const float*)d_in[0];
    const int*   seg  = (const int*)d_in[1];
    const float* A    = (const float*)d_in[2];
    const float* B    = (const float*)d_in[3];
    const float* bias = (const float*)d_in[4];
    float* out = (float*)d_out;

    const int n_tokens = in_sizes[1];

    lora_grouped<<<NSEG * NCHUNK, 256, 0, stream>>>(x, seg, A, B, bias, out, n_tokens);
}

// Round 4
// 120.769 us; speedup vs baseline: 1.2044x; 1.2044x over previous
//
#include <hip/hip_runtime.h>

#define HID 1024
#define RANK 16
#define NSEG 64
#define NCHUNK 16          // grid = 64*16 = 1024 blocks, chunk = 512 tokens
#define NXCD 8

__global__ __launch_bounds__(256) void lora_v4(
    const float* __restrict__ x,      // [N, H]
    const int*   __restrict__ seg,    // [N]
    const float* __restrict__ A,      // [S, H, R]
    const float* __restrict__ B,      // [S, R, H]
    const float* __restrict__ bias,   // [S, H]
    float*       __restrict__ out,    // [N, H]
    int N)
{
    // XCD-bijective swizzle (1024 = 8*128): each XCD owns 8 segments.
    const int work = (blockIdx.x & (NXCD - 1)) * ((NSEG * NCHUNK) / NXCD)
                   + (blockIdx.x >> 3);
    const int s = work >> 4;                  // NCHUNK == 16
    const int c = work & (NCHUNK - 1);
    const int tid  = threadIdx.x;
    const int lane = tid & 63;
    const int wave = tid >> 6;

    __shared__ int   list[512];
    __shared__ int   cnt;
    __shared__ float red[4][16][68];          // per-wave transpose-reduce pad
    __shared__ float inter_lds[2][4][RANK];   // double-buffered -> 1 barrier/group

    if (tid == 0) cnt = 0;

    // A + bias: issue early, independent of the scan.
    const float4* A4 = (const float4*)(A + (size_t)s * HID * RANK);
    float4 av[4][4];                          // row tid*4+jh, r-quad q
    #pragma unroll
    for (int jh = 0; jh < 4; ++jh)
        #pragma unroll
        for (int q = 0; q < 4; ++q)
            av[jh][q] = A4[(size_t)(tid * 4 + jh) * (RANK / 4) + q];
    const float4 bia = ((const float4*)(bias + (size_t)s * HID))[tid];

    __syncthreads();                          // cnt=0 visible

    // ---- scan 512-token slice ----
    const int chunkN = (N + NCHUNK - 1) / NCHUNK;
    const int i0 = c * chunkN;
    const int i1 = min(N, i0 + chunkN);
    for (int i = i0 + tid; i < i1; i += 256)
        if (seg[i] == s) list[atomicAdd(&cnt, 1)] = i;
    __syncthreads();
    const int m = cnt;
    if (m == 0) return;

    const float4* B4 = (const float4*)(B + (size_t)s * RANK * HID);
    const int v = lane & 15;                  // reduce: value owned by lane
    const int q = lane >> 4;                  // quarter summed by lane

    for (int t = 0; t < m; t += 4) {
        const int nt = min(4, m - t);
        int n[4];
        #pragma unroll
        for (int j = 0; j < 4; ++j)
            n[j] = list[t + (j < nt ? j : nt - 1)];

        // Phase 1: wave owns r = 4*wave+rr; lane covers h = lane*16..+15
        float4 xv[4][4];
        #pragma unroll
        for (int j = 0; j < 4; ++j) {
            const float4* xr = (const float4*)(x + (size_t)n[j] * HID);
            #pragma unroll
            for (int k = 0; k < 4; ++k) xv[j][k] = xr[lane * 4 + k];
        }

        float acc[4][4];
        #pragma unroll
        for (int rr = 0; rr < 4; ++rr)
            #pragma unroll
            for (int j = 0; j < 4; ++j) acc[rr][j] = 0.f;

        #pragma unroll
        for (int rr = 0; rr < 4; ++rr) {
            const float4* Br = B4 + (size_t)(wave * 4 + rr) * (HID / 4);
            #pragma unroll
            for (int k = 0; k < 4; ++k) {
                float4 b = Br[lane * 4 + k];
                #pragma unroll
                for (int j = 0; j < 4; ++j)
                    acc[rr][j] += b.x * xv[j][k].x + b.y * xv[j][k].y
                                + b.z * xv[j][k].z + b.w * xv[j][k].w;
            }
        }

        // Transpose-reduce (wave-local; LDS pipe is in-order per wave).
        #pragma unroll
        for (int rr = 0; rr < 4; ++rr)
            #pragma unroll
            for (int j = 0; j < 4; ++j)
                red[wave][rr * 4 + j][lane] = acc[rr][j];   // conflict-free

        const float4* rp = (const float4*)&red[wave][v][q * 16];
        float4 r0 = rp[0], r1 = rp[1], r2 = rp[2], r3 = rp[3];
        float sum = ((r0.x + r0.y) + (r0.z + r0.w))
                  + ((r1.x + r1.y) + (r1.z + r1.w))
                  + ((r2.x + r2.y) + (r2.z + r2.w))
                  + ((r3.x + r3.y) + (r3.z + r3.w));
        sum += __shfl_xor(sum, 16, 64);
        sum += __shfl_xor(sum, 32, 64);

        const int buf = (t >> 2) & 1;
        if (lane < 16)                         // v = rr*4+j -> r=4*wave+rr, tok j
            inter_lds[buf][v & 3][wave * 4 + (v >> 2)] = sum;
        __syncthreads();                       // the ONLY barrier per group

        // Phase 2: thread owns h = tid*4..+3 (A already in registers)
        #pragma unroll
        for (int j = 0; j < 4; ++j) {
            const float4* I4 = (const float4*)inter_lds[buf][j];
            float4 iv[4];
            #pragma unroll
            for (int qq = 0; qq < 4; ++qq) iv[qq] = I4[qq];
            float4 o = bia;
            float* op = (float*)&o;
            #pragma unroll
            for (int jh = 0; jh < 4; ++jh) {
                float a = 0.f;
                #pragma unroll
                for (int qq = 0; qq < 4; ++qq)
                    a += av[jh][qq].x * iv[qq].x + av[jh][qq].y * iv[qq].y
                       + av[jh][qq].z * iv[qq].z + av[jh][qq].w * iv[qq].w;
                op[jh] += a;
            }
            if (j < nt)
                ((float4*)(out + (size_t)n[j] * HID))[tid] = o;
        }
    }
}

extern "C" void kernel_launch(void* const* d_in, const int* in_sizes, int n_in,
                              void* d_out, int out_size, void* d_ws, size_t ws_size,
                              hipStream_t stream) {
    const float* x    = (const float*)d_in[0];
    const int*   seg  = (const int*)d_in[1];
    const float* A    = (const float*)d_in[2];
    const float* B    = (const float*)d_in[3];
    const float* bias = (const float*)d_in[4];
    float* out = (float*)d_out;

    const int n_tokens = in_sizes[1];

    lora_v4<<<NSEG * NCHUNK, 256, 0, stream>>>(x, seg, A, B, bias, out, n_tokens);
}

// Round 5
// 114.677 us; speedup vs baseline: 1.2684x; 1.0531x over previous
//
#include <hip/hip_runtime.h>

#define HID 1024
#define RANK 16
#define NSEG 64
#define NCHUNK 16          // grid = 64*16 = 1024 blocks, chunk = 512 tokens
#define NXCD 8

__global__ __launch_bounds__(256) void lora_v5(
    const float* __restrict__ x,      // [N, H]
    const int*   __restrict__ seg,    // [N]
    const float* __restrict__ A,      // [S, H, R]
    const float* __restrict__ B,      // [S, R, H]
    const float* __restrict__ bias,   // [S, H]
    float*       __restrict__ out,    // [N, H]
    int N)
{
    // XCD-bijective swizzle (1024 = 8*128): each XCD owns 8 segments.
    const int work = (blockIdx.x & (NXCD - 1)) * ((NSEG * NCHUNK) / NXCD)
                   + (blockIdx.x >> 3);
    const int s = work >> 4;                  // NCHUNK == 16
    const int c = work & (NCHUNK - 1);
    const int tid  = threadIdx.x;
    const int lane = tid & 63;
    const int wave = tid >> 6;

    __shared__ int   list[512];
    __shared__ int   cnt;
    __shared__ float red[4][16][68];          // per-wave transpose-reduce pad
    __shared__ float inter_lds[2][4][RANK];   // double-buffered -> 1 barrier/group

    if (tid == 0) cnt = 0;

    // A + bias: issue early, independent of the scan. (one-time, per block)
    const float4* A4 = (const float4*)(A + (size_t)s * HID * RANK);
    float4 av[4][4];                          // row tid*4+jh, r-quad q
    #pragma unroll
    for (int jh = 0; jh < 4; ++jh)
        #pragma unroll
        for (int q = 0; q < 4; ++q)
            av[jh][q] = A4[(size_t)(tid * 4 + jh) * (RANK / 4) + q];
    const float4 bia = ((const float4*)(bias + (size_t)s * HID))[tid];

    __syncthreads();                          // cnt=0 visible

    // ---- scan 512-token slice (coalesced) ----
    const int chunkN = (N + NCHUNK - 1) / NCHUNK;
    const int i0 = c * chunkN;
    const int i1 = min(N, i0 + chunkN);
    for (int i = i0 + tid; i < i1; i += 256)
        if (seg[i] == s) list[atomicAdd(&cnt, 1)] = i;
    __syncthreads();
    const int m = cnt;
    if (m == 0) return;

    const float4* B4 = (const float4*)(B + (size_t)s * RANK * HID);
    const int v = lane & 15;                  // reduce: value owned by lane
    const int q = lane >> 4;                  // quarter summed by lane

    for (int t = 0; t < m; t += 4) {
        const int nt = min(4, m - t);
        int n[4];
        #pragma unroll
        for (int j = 0; j < 4; ++j)
            n[j] = list[t + (j < nt ? j : nt - 1)];

        // Phase 1: inter[j][r] = sum_h B[s][r][h] * x[n[j]][h]
        // COALESCED map: load idx = k*64 + lane -> lane i reads bytes i*16
        // within a contiguous 1KB span per instruction. Lane's h-ownership
        // h = k*256 + lane*4..+3 (interleaved) — reduction covers all lanes.
        float4 xv[4][4];
        #pragma unroll
        for (int j = 0; j < 4; ++j) {
            const float4* xr = (const float4*)(x + (size_t)n[j] * HID);
            #pragma unroll
            for (int k = 0; k < 4; ++k) xv[j][k] = xr[k * 64 + lane];
        }

        float acc[4][4];
        #pragma unroll
        for (int rr = 0; rr < 4; ++rr)
            #pragma unroll
            for (int j = 0; j < 4; ++j) acc[rr][j] = 0.f;

        #pragma unroll
        for (int rr = 0; rr < 4; ++rr) {
            const float4* Br = B4 + (size_t)(wave * 4 + rr) * (HID / 4);
            #pragma unroll
            for (int k = 0; k < 4; ++k) {
                float4 b = Br[k * 64 + lane];          // coalesced
                #pragma unroll
                for (int j = 0; j < 4; ++j)
                    acc[rr][j] += b.x * xv[j][k].x + b.y * xv[j][k].y
                                + b.z * xv[j][k].z + b.w * xv[j][k].w;
            }
        }

        // Transpose-reduce (wave-local; LDS pipe is in-order per wave).
        #pragma unroll
        for (int rr = 0; rr < 4; ++rr)
            #pragma unroll
            for (int j = 0; j < 4; ++j)
                red[wave][rr * 4 + j][lane] = acc[rr][j];   // conflict-free

        const float4* rp = (const float4*)&red[wave][v][q * 16];
        float4 r0 = rp[0], r1 = rp[1], r2 = rp[2], r3 = rp[3];
        float sum = ((r0.x + r0.y) + (r0.z + r0.w))
                  + ((r1.x + r1.y) + (r1.z + r1.w))
                  + ((r2.x + r2.y) + (r2.z + r2.w))
                  + ((r3.x + r3.y) + (r3.z + r3.w));
        sum += __shfl_xor(sum, 16, 64);
        sum += __shfl_xor(sum, 32, 64);

        const int buf = (t >> 2) & 1;
        if (lane < 16)                         // v = rr*4+j -> r=4*wave+rr, tok j
            inter_lds[buf][v & 3][wave * 4 + (v >> 2)] = sum;
        __syncthreads();                       // the ONLY barrier per group

        // Phase 2: thread owns h = tid*4..+3 (A already in registers)
        #pragma unroll
        for (int j = 0; j < 4; ++j) {
            const float4* I4 = (const float4*)inter_lds[buf][j];
            float4 iv[4];
            #pragma unroll
            for (int qq = 0; qq < 4; ++qq) iv[qq] = I4[qq];
            float4 o = bia;
            float* op = (float*)&o;
            #pragma unroll
            for (int jh = 0; jh < 4; ++jh) {
                float a = 0.f;
                #pragma unroll
                for (int qq = 0; qq < 4; ++qq)
                    a += av[jh][qq].x * iv[qq].x + av[jh][qq].y * iv[qq].y
                       + av[jh][qq].z * iv[qq].z + av[jh][qq].w * iv[qq].w;
                op[jh] += a;
            }
            if (j < nt)
                ((float4*)(out + (size_t)n[j] * HID))[tid] = o;
        }
    }
}

extern "C" void kernel_launch(void* const* d_in, const int* in_sizes, int n_in,
                              void* d_out, int out_size, void* d_ws, size_t ws_size,
                              hipStream_t stream) {
    const float* x    = (const float*)d_in[0];
    const int*   seg  = (const int*)d_in[1];
    const float* A    = (const float*)d_in[2];
    const float* B    = (const float*)d_in[3];
    const float* bias = (const float*)d_in[4];
    float* out = (float*)d_out;

    const int n_tokens = in_sizes[1];

    lora_v5<<<NSEG * NCHUNK, 256, 0, stream>>>(x, seg, A, B, bias, out, n_tokens);
}